// Round 1
// baseline (498.724 us; speedup 1.0000x reference)
//
#include <hip/hip_runtime.h>
#include <hip/hip_fp16.h>

typedef _Float16 f16;
typedef _Float16 f16x8 __attribute__((ext_vector_type(8)));
typedef _Float16 f16x4 __attribute__((ext_vector_type(4)));
typedef float f32x4 __attribute__((ext_vector_type(4)));

#define DEV static __device__ __forceinline__

DEV void async_copy16(const f16* gsrc, f16* ldst) {
    __builtin_amdgcn_global_load_lds(
        (const __attribute__((address_space(1))) void*)gsrc,
        (__attribute__((address_space(3))) void*)ldst,
        16, 0, 0);
}

// ---------------------------------------------------------------------------
// Split rows x 1024 fp32 -> rows x 2048 fp16  (cols 0..1023 = hi, 1024..2047 = lo)
// grid = rows, block = 256 (each thread 4 elems via float4)
__global__ void split_rows_k(const float* __restrict__ src, f16* __restrict__ dst) {
    const int row = blockIdx.x;
    const int c4  = threadIdx.x;
    float4 v = reinterpret_cast<const float4*>(src + (size_t)row * 1024)[c4];
    float vv[4] = {v.x, v.y, v.z, v.w};
    f16x4 hi, lo;
    #pragma unroll
    for (int i = 0; i < 4; i++) {
        f16 h = (f16)vv[i];
        hi[i] = h;
        lo[i] = (f16)(vv[i] - (float)h);
    }
    f16* base = dst + (size_t)row * 2048 + c4 * 4;
    *reinterpret_cast<f16x4*>(base)        = hi;
    *reinterpret_cast<f16x4*>(base + 1024) = lo;
}

// ---------------------------------------------------------------------------
// local [16][1024 l][1024 d] fp32 ->
//   localS [16][l][2048] fp16 (hi|lo)   (for scores GEMM, B^T layout over d)
//   localT [16][d][1024 l] fp16         (for PV GEMM, B^T layout over l)
// grid = (d_tiles=16, l_tiles=16, b=16), block = 256, 64x64 tile transpose
__global__ void split_local_k(const float* __restrict__ local,
                              f16* __restrict__ localS, f16* __restrict__ localT) {
    __shared__ float tile[64][65];
    const int b  = blockIdx.z;
    const int l0 = blockIdx.y * 64;
    const int d0 = blockIdx.x * 64;
    const int tr = threadIdx.x >> 6;   // 0..3
    const int tc = threadIdx.x & 63;   // 0..63
    const float* src = local + ((size_t)b * 1024 + l0) * 1024 + d0;
    #pragma unroll
    for (int rr = 0; rr < 16; rr++) {
        int r = rr * 4 + tr;
        float x = src[(size_t)r * 1024 + tc];
        tile[r][tc] = x;
        f16 h = (f16)x;
        size_t o = ((size_t)b * 1024 + l0 + r) * 2048 + d0 + tc;
        localS[o]        = h;
        localS[o + 1024] = (f16)(x - (float)h);
    }
    __syncthreads();
    f16* dstT = localT + ((size_t)b * 1024 + d0) * 1024 + l0;
    #pragma unroll
    for (int rr = 0; rr < 16; rr++) {
        int r = rr * 4 + tr;
        dstT[(size_t)r * 1024 + tc] = (f16)tile[tc][r];
    }
}

// ---------------------------------------------------------------------------
// B^T-layout fp16 GEMM: C[m,n] = sum_k A[m,k] * B[n,k]
// 128x128 tile, BK=64, 256 threads (4 waves, 2x2), mfma_f32_16x16x32_f16.
// lda = ldb = K.  EPI=0: +bias then split-write hi/lo fp16 to Cs (ld 2N).
//                 EPI=1: fp32 write to Cf (ld N).
template <int EPI>
__launch_bounds__(256)
__global__ void gemm_bt_k(const f16* __restrict__ A, const f16* __restrict__ B,
                          float* __restrict__ Cf, f16* __restrict__ Cs,
                          const float* __restrict__ bias,
                          int N, int K, long sA, long sB, long sC) {
    __shared__ f16 Alds[128 * 64];
    __shared__ f16 Blds[128 * 64];
    const int tid  = threadIdx.x;
    const int bm   = blockIdx.x, bn = blockIdx.y, bz = blockIdx.z;
    const int lane = tid & 63;
    const int w    = tid >> 6;
    const int wr   = w >> 1, wc = w & 1;
    const f16* Ab = A + (size_t)bz * sA + (size_t)(bm * 128) * K;
    const f16* Bb = B + (size_t)bz * sB + (size_t)(bn * 128) * K;

    const int grow = tid >> 3;        // 0..31 (row within 32-row staging round)
    const int gcol = (tid & 7) * 8;   // k-element offset within BK

    f32x4 acc[4][4] = {};

    for (int k0 = 0; k0 < K; k0 += 64) {
        #pragma unroll
        for (int r = 0; r < 4; r++) {
            int row = r * 32 + grow;
            async_copy16(Ab + (size_t)row * K + k0 + gcol, &Alds[r * 2048 + tid * 8]);
        }
        #pragma unroll
        for (int r = 0; r < 4; r++) {
            int row = r * 32 + grow;
            async_copy16(Bb + (size_t)row * K + k0 + gcol, &Blds[r * 2048 + tid * 8]);
        }
        __syncthreads();
        #pragma unroll
        for (int kk = 0; kk < 64; kk += 32) {
            f16x8 af[4], bf[4];
            #pragma unroll
            for (int i = 0; i < 4; i++)
                af[i] = *reinterpret_cast<const f16x8*>(
                    &Alds[(64 * wr + 16 * i + (lane & 15)) * 64 + kk + 8 * (lane >> 4)]);
            #pragma unroll
            for (int j = 0; j < 4; j++)
                bf[j] = *reinterpret_cast<const f16x8*>(
                    &Blds[(64 * wc + 16 * j + (lane & 15)) * 64 + kk + 8 * (lane >> 4)]);
            #pragma unroll
            for (int i = 0; i < 4; i++)
                #pragma unroll
                for (int j = 0; j < 4; j++)
                    acc[i][j] = __builtin_amdgcn_mfma_f32_16x16x32_f16(af[i], bf[j], acc[i][j], 0, 0, 0);
        }
        __syncthreads();
    }

    const int r4 = (lane >> 4) * 4;
    const int cl = lane & 15;
    #pragma unroll
    for (int i = 0; i < 4; i++) {
        #pragma unroll
        for (int j = 0; j < 4; j++) {
            const int row0 = bm * 128 + 64 * wr + 16 * i + r4;
            const int col  = bn * 128 + 64 * wc + 16 * j + cl;
            if constexpr (EPI == 0) {
                float bv = bias[col];
                #pragma unroll
                for (int r = 0; r < 4; r++) {
                    float v = acc[i][j][r] + bv;
                    f16 h = (f16)v;
                    size_t o = (size_t)(row0 + r) * (2 * N) + col;
                    Cs[o]     = h;
                    Cs[o + N] = (f16)(v - (float)h);
                }
            } else {
                #pragma unroll
                for (int r = 0; r < 4; r++)
                    Cf[(size_t)bz * sC + (size_t)(row0 + r) * N + col] = acc[i][j][r];
            }
        }
    }
}

// ---------------------------------------------------------------------------
// Row softmax: scores [rows][1024] fp32 -> attn [rows][1024] fp16
// grid = rows, block = 256 (4 elems/thread)
__global__ void softmax_k(const float* __restrict__ S, f16* __restrict__ P) {
    __shared__ float red[8];
    const int row = blockIdx.x;
    const int t = threadIdx.x;
    const int wv = t >> 6, ln = t & 63;
    float4 v = reinterpret_cast<const float4*>(S + (size_t)row * 1024)[t];
    float m = fmaxf(fmaxf(v.x, v.y), fmaxf(v.z, v.w));
    #pragma unroll
    for (int off = 1; off < 64; off <<= 1) m = fmaxf(m, __shfl_xor(m, off));
    if (ln == 0) red[wv] = m;
    __syncthreads();
    m = fmaxf(fmaxf(red[0], red[1]), fmaxf(red[2], red[3]));
    float e0 = __expf(v.x - m), e1 = __expf(v.y - m), e2 = __expf(v.z - m), e3 = __expf(v.w - m);
    float s = e0 + e1 + e2 + e3;
    #pragma unroll
    for (int off = 1; off < 64; off <<= 1) s += __shfl_xor(s, off);
    if (ln == 0) red[4 + wv] = s;
    __syncthreads();
    s = red[4] + red[5] + red[6] + red[7];
    float inv = 1.0f / s;
    f16x4 o;
    o[0] = (f16)(e0 * inv); o[1] = (f16)(e1 * inv); o[2] = (f16)(e2 * inv); o[3] = (f16)(e3 * inv);
    *reinterpret_cast<f16x4*>(P + (size_t)row * 1024 + t * 4) = o;
}

// ---------------------------------------------------------------------------
extern "C" void kernel_launch(void* const* d_in, const int* in_sizes, int n_in,
                              void* d_out, int out_size, void* d_ws, size_t ws_size,
                              hipStream_t stream) {
    const float* text  = (const float*)d_in[0];  // [16,1024,1024]
    const float* local = (const float*)d_in[1];  // [16,1024,1024]
    const float* Ww    = (const float*)d_in[2];  // [1024,1024]
    const float* Wb    = (const float*)d_in[3];  // [1024]
    float* out = (float*)d_out;                  // [16,1024,1024] fp32

    char* ws = (char*)d_ws;
    const size_t MB = 1024 * 1024;
    f16*   textS  = (f16*)(ws);                 // 64MB [16384][2048]  (dead after proj)
    f16*   WS     = (f16*)(ws + 64 * MB);       //  4MB [1024][2048]
    f16*   localS = (f16*)(ws + 68 * MB);       // 64MB [16][1024][2048]
    f16*   localT = (f16*)(ws + 132 * MB);      // 32MB [16][1024][1024]
    f16*   projS  = (f16*)(ws + 164 * MB);      // 64MB [16384][2048]  (dead after scores)
    float* scores = (float*)(ws);               // 64MB, reuses textS region
    f16*   attn   = (f16*)(ws + 164 * MB);      // 32MB, reuses projS region

    // 1. split text and W into fp16 hi|lo
    hipLaunchKernelGGL(split_rows_k, dim3(16384), dim3(256), 0, stream, text, textS);
    hipLaunchKernelGGL(split_rows_k, dim3(1024), dim3(256), 0, stream, Ww, WS);
    // 2. split local -> localS (hi|lo) and transposed localT (fp16)
    hipLaunchKernelGGL(split_local_k, dim3(16, 16, 16), dim3(256), 0, stream,
                       local, localS, localT);
    // 3. proj = text @ W^T + b   (M=16384, N=1024, K'=2048), split-write
    hipLaunchKernelGGL((gemm_bt_k<0>), dim3(128, 8, 1), dim3(256), 0, stream,
                       textS, WS, (float*)nullptr, projS, Wb,
                       1024, 2048, 0L, 0L, 0L);
    // 4. scores[b] = proj[b] @ local[b]^T   (per batch 1024x1024, K'=2048)
    hipLaunchKernelGGL((gemm_bt_k<1>), dim3(8, 8, 16), dim3(256), 0, stream,
                       projS, localS, scores, (f16*)nullptr, (const float*)nullptr,
                       1024, 2048, (long)1024 * 2048, (long)1024 * 2048, (long)1024 * 1024);
    // 5. softmax over l -> attn fp16
    hipLaunchKernelGGL(softmax_k, dim3(16384), dim3(256), 0, stream, scores, attn);
    // 6. out[b] = attn[b] @ localT[b]^T  (= attn @ local), K=1024
    hipLaunchKernelGGL((gemm_bt_k<1>), dim3(8, 8, 16), dim3(256), 0, stream,
                       attn, localT, out, (f16*)nullptr, (const float*)nullptr,
                       1024, 1024, (long)1024 * 1024, (long)1024 * 1024, (long)1024 * 1024);
}

// Round 2
// 407.030 us; speedup vs baseline: 1.2253x; 1.2253x over previous
//
#include <hip/hip_runtime.h>
#include <hip/hip_fp16.h>

typedef _Float16 f16;
typedef _Float16 f16x8 __attribute__((ext_vector_type(8)));
typedef _Float16 f16x4 __attribute__((ext_vector_type(4)));
typedef float f32x4 __attribute__((ext_vector_type(4)));

#define DEV static __device__ __forceinline__
#define VMCNT(n) asm volatile("s_waitcnt vmcnt(" #n ")" ::: "memory")

DEV void barfence() {
    __builtin_amdgcn_s_barrier();
    asm volatile("" ::: "memory");
}

DEV void async_copy16(const f16* gsrc, f16* ldst) {
    __builtin_amdgcn_global_load_lds(
        (const __attribute__((address_space(1))) void*)gsrc,
        (__attribute__((address_space(3))) void*)ldst,
        16, 0, 0);
}

// ---------------------------------------------------------------------------
// rows x 1024 fp32 -> rows x 2048 f16 (hi | lo), grid-stride over float4s
__global__ void split_rows_k(const float* __restrict__ src, f16* __restrict__ dst, int n4) {
    for (int idx = blockIdx.x * 256 + threadIdx.x; idx < n4; idx += gridDim.x * 256) {
        int row = idx >> 8, c4 = idx & 255;
        float4 v = reinterpret_cast<const float4*>(src)[idx];
        float vv[4] = {v.x, v.y, v.z, v.w};
        f16x4 hi, lo;
        #pragma unroll
        for (int i = 0; i < 4; i++) {
            f16 h = (f16)vv[i];
            hi[i] = h;
            lo[i] = (f16)(vv[i] - (float)h);
        }
        f16* base = dst + (size_t)row * 2048 + c4 * 4;
        *reinterpret_cast<f16x4*>(base)        = hi;
        *reinterpret_cast<f16x4*>(base + 1024) = lo;
    }
}

// ---------------------------------------------------------------------------
// local [16][l][d] fp32 -> localS [16][l][2048] (hi|lo) and localT [16][d][l] f16
__global__ void split_local_k(const float* __restrict__ local,
                              f16* __restrict__ localS, f16* __restrict__ localT) {
    __shared__ float tile[64][65];
    const int b  = blockIdx.z;
    const int l0 = blockIdx.y * 64;
    const int d0 = blockIdx.x * 64;
    const int r  = threadIdx.x >> 4;   // 0..15
    const int c4 = threadIdx.x & 15;   // 0..15
    const float* src = local + ((size_t)b * 1024 + l0) * 1024 + d0;
    #pragma unroll
    for (int rr = 0; rr < 4; rr++) {
        int row = rr * 16 + r;
        float4 v = *reinterpret_cast<const float4*>(src + (size_t)row * 1024 + c4 * 4);
        float vv[4] = {v.x, v.y, v.z, v.w};
        f16x4 hi, lo;
        #pragma unroll
        for (int e = 0; e < 4; e++) {
            tile[row][c4 * 4 + e] = vv[e];
            f16 h = (f16)vv[e];
            hi[e] = h;
            lo[e] = (f16)(vv[e] - (float)h);
        }
        f16* o = localS + ((size_t)b * 1024 + l0 + row) * 2048 + d0 + c4 * 4;
        *reinterpret_cast<f16x4*>(o)        = hi;
        *reinterpret_cast<f16x4*>(o + 1024) = lo;
    }
    __syncthreads();
    #pragma unroll
    for (int rr = 0; rr < 4; rr++) {
        int d = rr * 16 + r;
        f16x4 o;
        #pragma unroll
        for (int e = 0; e < 4; e++) o[e] = (f16)tile[c4 * 4 + e][d];
        *reinterpret_cast<f16x4*>(localT + ((size_t)b * 1024 + d0 + d) * 1024 + l0 + c4 * 4) = o;
    }
}

// ---------------------------------------------------------------------------
// 256x256 tile, BK=64, 8 waves (2Mx4N), 3-phase pipelined K-loop, swizzled LDS.
// C[m,n] = sum_k A[m,k]*B[n,k].  EPI0: +bias, split hi/lo f16 (ld 2N). EPI1: f32.
DEV void load_af(const f16* lds, int base, int c0, int c1, f16x8 (&a)[4][2]) {
    #pragma unroll
    for (int i = 0; i < 4; i++) {
        a[i][0] = *reinterpret_cast<const f16x8*>(&lds[base + i * 1024 + c0]);
        a[i][1] = *reinterpret_cast<const f16x8*>(&lds[base + i * 1024 + c1]);
    }
}
DEV void load_bf(const f16* lds, int base, int c0, int c1, f16x8 (&b)[2][2]) {
    #pragma unroll
    for (int j = 0; j < 2; j++) {
        b[j][0] = *reinterpret_cast<const f16x8*>(&lds[base + j * 1024 + c0]);
        b[j][1] = *reinterpret_cast<const f16x8*>(&lds[base + j * 1024 + c1]);
    }
}
template <int Q>
DEV void mfma16(const f16x8 (&a)[4][2], const f16x8 (&b)[2][2], f32x4 (&acc)[4][4][2]) {
    __builtin_amdgcn_s_setprio(1);
    #pragma unroll
    for (int i = 0; i < 4; i++)
        #pragma unroll
        for (int j = 0; j < 2; j++) {
            acc[Q][i][j] = __builtin_amdgcn_mfma_f32_16x16x32_f16(a[i][0], b[j][0], acc[Q][i][j], 0, 0, 0);
            acc[Q][i][j] = __builtin_amdgcn_mfma_f32_16x16x32_f16(a[i][1], b[j][1], acc[Q][i][j], 0, 0, 0);
        }
    __builtin_amdgcn_s_setprio(0);
}

template <int EPI>
__launch_bounds__(512)
__global__ void gemm256_k(const f16* __restrict__ A, const f16* __restrict__ B,
                          float* __restrict__ Cf, f16* __restrict__ Cs,
                          const float* __restrict__ bias,
                          int N, int K, long sA, long sB, long sC) {
    extern __shared__ f16 lds[];   // 65536 f16 = 128 KiB: [buf][A|B][half][128*64]
    const int tid  = threadIdx.x;
    const int lane = tid & 63;
    const int w    = tid >> 6;          // 0..7
    const int wr   = w >> 2, wc = w & 3;
    const int bm = blockIdx.x, bn = blockIdx.y, bz = blockIdx.z;
    const f16* Ab = A + (size_t)bz * sA + (size_t)(bm * 256) * K;
    const f16* Bb = B + (size_t)bz * sB + (size_t)(bn * 256) * K;
    // staging constants: lane -> (row-in-8, swizzled src slot)
    const int rloc = lane >> 3;                     // 0..7
    const int sl8  = ((lane & 7) ^ rloc) * 8;       // src k-offset (pre-swizzle)
    // frag-read constants: col = (kk*32 | 8*(lane>>4)) ^ (8*(lane&7))
    const int lrow = lane & 15;
    const int c0 = (8 * (lane >> 4)) ^ (8 * (lane & 7));
    const int c1 = c0 ^ 32;
    const int abase = (wr * 64 + lrow) * 64;
    const int bbase = (wc * 32 + lrow) * 64;

    auto stageA = [&](int sb, int half, int k0) {
        #pragma unroll
        for (int i = 0; i < 2; i++) {
            int rr = (w * 2 + i) * 8 + rloc;
            async_copy16(Ab + (size_t)(half * 128 + rr) * K + k0 + sl8,
                         &lds[sb + half * 8192 + (w * 2 + i) * 512 + lane * 8]);
        }
    };
    auto stageB = [&](int sb, int half, int k0) {
        #pragma unroll
        for (int i = 0; i < 2; i++) {
            int rr = (w * 2 + i) * 8 + rloc;
            async_copy16(Bb + (size_t)(half * 128 + rr) * K + k0 + sl8,
                         &lds[sb + 16384 + half * 8192 + (w * 2 + i) * 512 + lane * 8]);
        }
    };

    f32x4 acc[4][4][2] = {};
    const int nt = K >> 6;

    // prologue: stage tile 0 into buf 0 (order: A0,B0,B1,A1), wait A0,B0
    stageA(0, 0, 0); stageB(0, 0, 0);
    stageB(0, 1, 0); stageA(0, 1, 0);
    VMCNT(4);
    barfence();

    for (int t = 0; t < nt - 1; ++t) {
        const int cb = (t & 1) * 32768;
        const int sb = cb ^ 32768;
        const int kn = (t + 1) * 64;
        f16x8 af[4][2], bf0[2][2], bf1[2][2];
        // P0: A-half0 + B-half0 frags; stage A0',B0'
        load_af(lds, cb + abase, c0, c1, af);
        load_bf(lds, cb + 16384 + bbase, c0, c1, bf0);
        stageA(sb, 0, kn); stageB(sb, 0, kn);
        barfence();
        mfma16<0>(af, bf0, acc);      // (M0,N0)
        VMCNT(6);
        barfence();
        // P1: B-half1 frags; stage B1'
        load_bf(lds, cb + 16384 + 8192 + bbase, c0, c1, bf1);
        stageB(sb, 1, kn);
        barfence();
        mfma16<1>(af, bf1, acc);      // (M0,N1)
        VMCNT(6);
        barfence();
        // P2: A-half1 frags; stage A1'; two MFMA clusters
        load_af(lds, cb + 8192 + abase, c0, c1, af);
        stageA(sb, 1, kn);
        barfence();
        mfma16<2>(af, bf0, acc);      // (M1,N0)
        mfma16<3>(af, bf1, acc);      // (M1,N1)
        VMCNT(4);
        barfence();
    }
    // peeled last tile (no staging, strict waits)
    {
        const int cb = ((nt - 1) & 1) * 32768;
        f16x8 af[4][2], bf0[2][2], bf1[2][2];
        load_af(lds, cb + abase, c0, c1, af);
        load_bf(lds, cb + 16384 + bbase, c0, c1, bf0);
        barfence();
        mfma16<0>(af, bf0, acc);
        VMCNT(2);
        barfence();
        load_bf(lds, cb + 16384 + 8192 + bbase, c0, c1, bf1);
        barfence();
        mfma16<1>(af, bf1, acc);
        VMCNT(0);
        barfence();
        load_af(lds, cb + 8192 + abase, c0, c1, af);
        barfence();
        mfma16<2>(af, bf0, acc);
        mfma16<3>(af, bf1, acc);
    }

    // epilogue: q -> (mh=q>>1, nh=q&1)
    const int r4 = (lane >> 4) * 4, cl = lane & 15;
    #pragma unroll
    for (int q = 0; q < 4; q++)
        #pragma unroll
        for (int i = 0; i < 4; i++)
            #pragma unroll
            for (int j = 0; j < 2; j++) {
                const int row0 = bm * 256 + (q >> 1) * 128 + wr * 64 + i * 16 + r4;
                const int col  = bn * 256 + (q & 1) * 128 + wc * 32 + j * 16 + cl;
                if constexpr (EPI == 0) {
                    float bv = bias[col];
                    #pragma unroll
                    for (int r = 0; r < 4; r++) {
                        float v = acc[q][i][j][r] + bv;
                        f16 h = (f16)v;
                        size_t o = (size_t)(row0 + r) * (2 * N) + col;
                        Cs[o]     = h;
                        Cs[o + N] = (f16)(v - (float)h);
                    }
                } else {
                    #pragma unroll
                    for (int r = 0; r < 4; r++)
                        Cf[(size_t)bz * sC + (size_t)(row0 + r) * N + col] = acc[q][i][j][r];
                }
            }
}

// ---------------------------------------------------------------------------
// Row softmax: scores [rows][1024] fp32 -> attn [rows][1024] f16
__global__ void softmax_k(const float* __restrict__ S, f16* __restrict__ P) {
    __shared__ float red[8];
    const int row = blockIdx.x;
    const int t = threadIdx.x;
    const int wv = t >> 6, ln = t & 63;
    float4 v = reinterpret_cast<const float4*>(S + (size_t)row * 1024)[t];
    float m = fmaxf(fmaxf(v.x, v.y), fmaxf(v.z, v.w));
    #pragma unroll
    for (int off = 1; off < 64; off <<= 1) m = fmaxf(m, __shfl_xor(m, off));
    if (ln == 0) red[wv] = m;
    __syncthreads();
    m = fmaxf(fmaxf(red[0], red[1]), fmaxf(red[2], red[3]));
    float e0 = __expf(v.x - m), e1 = __expf(v.y - m), e2 = __expf(v.z - m), e3 = __expf(v.w - m);
    float s = e0 + e1 + e2 + e3;
    #pragma unroll
    for (int off = 1; off < 64; off <<= 1) s += __shfl_xor(s, off);
    if (ln == 0) red[4 + wv] = s;
    __syncthreads();
    s = red[4] + red[5] + red[6] + red[7];
    float inv = 1.0f / s;
    f16x4 o;
    o[0] = (f16)(e0 * inv); o[1] = (f16)(e1 * inv); o[2] = (f16)(e2 * inv); o[3] = (f16)(e3 * inv);
    *reinterpret_cast<f16x4*>(P + (size_t)row * 1024 + t * 4) = o;
}

// ---------------------------------------------------------------------------
extern "C" void kernel_launch(void* const* d_in, const int* in_sizes, int n_in,
                              void* d_out, int out_size, void* d_ws, size_t ws_size,
                              hipStream_t stream) {
    const float* text  = (const float*)d_in[0];  // [16,1024,1024]
    const float* local = (const float*)d_in[1];  // [16,1024,1024]
    const float* Ww    = (const float*)d_in[2];  // [1024,1024]
    const float* Wb    = (const float*)d_in[3];  // [1024]
    float* out = (float*)d_out;                  // [16,1024,1024] fp32

    char* ws = (char*)d_ws;
    const size_t MB = 1024 * 1024;
    f16*   textS  = (f16*)(ws);                 // 64MB (dead after proj)
    f16*   WS     = (f16*)(ws + 64 * MB);       //  4MB
    f16*   localS = (f16*)(ws + 68 * MB);       // 64MB
    f16*   localT = (f16*)(ws + 132 * MB);      // 32MB
    f16*   projS  = (f16*)(ws + 164 * MB);      // 64MB (dead after scores)
    float* scores = (float*)(ws);               // 64MB, reuses textS region
    f16*   attn   = (f16*)(ws + 164 * MB);      // 32MB, reuses projS region

    auto g0 = gemm256_k<0>;
    auto g1 = gemm256_k<1>;
    (void)hipFuncSetAttribute((const void*)g0, hipFuncAttributeMaxDynamicSharedMemorySize, 131072);
    (void)hipFuncSetAttribute((const void*)g1, hipFuncAttributeMaxDynamicSharedMemorySize, 131072);

    hipLaunchKernelGGL(split_rows_k, dim3(2048), dim3(256), 0, stream, text, textS, 16384 * 256);
    hipLaunchKernelGGL(split_rows_k, dim3(512), dim3(256), 0, stream, Ww, WS, 1024 * 256);
    hipLaunchKernelGGL(split_local_k, dim3(16, 16, 16), dim3(256), 0, stream,
                       local, localS, localT);
    // proj = text @ W^T + b  (M=16384, N=1024, K'=2048) -> split hi/lo
    hipLaunchKernelGGL(g0, dim3(64, 4, 1), dim3(512), 131072, stream,
                       textS, WS, (float*)nullptr, projS, Wb,
                       1024, 2048, 0L, 0L, 0L);
    // scores[b] = proj[b] @ local[b]^T  (1024x1024, K'=2048)
    hipLaunchKernelGGL(g1, dim3(4, 4, 16), dim3(512), 131072, stream,
                       projS, localS, scores, (f16*)nullptr, (const float*)nullptr,
                       1024, 2048, (long)1024 * 2048, (long)1024 * 2048, (long)1024 * 1024);
    hipLaunchKernelGGL(softmax_k, dim3(16384), dim3(256), 0, stream, scores, attn);
    // out[b] = attn[b] @ local[b]  (K=1024)
    hipLaunchKernelGGL(g1, dim3(4, 4, 16), dim3(512), 131072, stream,
                       attn, localT, out, (f16*)nullptr, (const float*)nullptr,
                       1024, 1024, (long)1024 * 1024, (long)1024 * 1024, (long)1024 * 1024);
}

// Round 4
// 395.781 us; speedup vs baseline: 1.2601x; 1.0284x over previous
//
#include <hip/hip_runtime.h>
#include <hip/hip_fp16.h>

typedef _Float16 f16;
typedef _Float16 f16x8 __attribute__((ext_vector_type(8)));
typedef _Float16 f16x4 __attribute__((ext_vector_type(4)));
typedef float f32x4 __attribute__((ext_vector_type(4)));

#define DEV static __device__ __forceinline__
#define VMCNT(n) asm volatile("s_waitcnt vmcnt(" #n ")" ::: "memory")

DEV void barfence() {
    __builtin_amdgcn_s_barrier();
    asm volatile("" ::: "memory");
}

DEV void async_copy16(const f16* gsrc, f16* ldst) {
    __builtin_amdgcn_global_load_lds(
        (const __attribute__((address_space(1))) void*)gsrc,
        (__attribute__((address_space(3))) void*)ldst,
        16, 0, 0);
}

// ---------------------------------------------------------------------------
// rows x 1024 fp32 -> rows x 2048 f16 (hi | lo), grid-stride over float4s
__global__ void split_rows_k(const float* __restrict__ src, f16* __restrict__ dst, int n4) {
    for (int idx = blockIdx.x * 256 + threadIdx.x; idx < n4; idx += gridDim.x * 256) {
        int row = idx >> 8, c4 = idx & 255;
        float4 v = reinterpret_cast<const float4*>(src)[idx];
        float vv[4] = {v.x, v.y, v.z, v.w};
        f16x4 hi, lo;
        #pragma unroll
        for (int i = 0; i < 4; i++) {
            f16 h = (f16)vv[i];
            hi[i] = h;
            lo[i] = (f16)(vv[i] - (float)h);
        }
        f16* base = dst + (size_t)row * 2048 + c4 * 4;
        *reinterpret_cast<f16x4*>(base)        = hi;
        *reinterpret_cast<f16x4*>(base + 1024) = lo;
    }
}

// ---------------------------------------------------------------------------
// local [16][l][d] fp32 -> localS [16][l][2048] (hi|lo) and localT [16][d][l] f16
__global__ void split_local_k(const float* __restrict__ local,
                              f16* __restrict__ localS, f16* __restrict__ localT) {
    __shared__ float tile[64][65];
    const int b  = blockIdx.z;
    const int l0 = blockIdx.y * 64;
    const int d0 = blockIdx.x * 64;
    const int r  = threadIdx.x >> 4;   // 0..15
    const int c4 = threadIdx.x & 15;   // 0..15
    const float* src = local + ((size_t)b * 1024 + l0) * 1024 + d0;
    #pragma unroll
    for (int rr = 0; rr < 4; rr++) {
        int row = rr * 16 + r;
        float4 v = *reinterpret_cast<const float4*>(src + (size_t)row * 1024 + c4 * 4);
        float vv[4] = {v.x, v.y, v.z, v.w};
        f16x4 hi, lo;
        #pragma unroll
        for (int e = 0; e < 4; e++) {
            tile[row][c4 * 4 + e] = vv[e];
            f16 h = (f16)vv[e];
            hi[e] = h;
            lo[e] = (f16)(vv[e] - (float)h);
        }
        f16* o = localS + ((size_t)b * 1024 + l0 + row) * 2048 + d0 + c4 * 4;
        *reinterpret_cast<f16x4*>(o)        = hi;
        *reinterpret_cast<f16x4*>(o + 1024) = lo;
    }
    __syncthreads();
    #pragma unroll
    for (int rr = 0; rr < 4; rr++) {
        int d = rr * 16 + r;
        f16x4 o;
        #pragma unroll
        for (int e = 0; e < 4; e++) o[e] = (f16)tile[c4 * 4 + e][d];
        *reinterpret_cast<f16x4*>(localT + ((size_t)b * 1024 + d0 + d) * 1024 + l0 + c4 * 4) = o;
    }
}

// ---------------------------------------------------------------------------
// 256x256 tile, BK=64, 8 waves (2Mx4N), 3-phase pipelined K-loop, swizzled LDS,
// XCD-aware 1D block swizzle (contiguous wgid chunk per XCD).
// C[m,n] = sum_k A[m,k]*B[n,k].  EPI0: +bias, split hi/lo f16 (ld 2N). EPI1: f32.
DEV void load_af(const f16* lds, int base, int c0, int c1, f16x8 (&a)[4][2]) {
    #pragma unroll
    for (int i = 0; i < 4; i++) {
        a[i][0] = *reinterpret_cast<const f16x8*>(&lds[base + i * 1024 + c0]);
        a[i][1] = *reinterpret_cast<const f16x8*>(&lds[base + i * 1024 + c1]);
    }
}
DEV void load_bf(const f16* lds, int base, int c0, int c1, f16x8 (&b)[2][2]) {
    #pragma unroll
    for (int j = 0; j < 2; j++) {
        b[j][0] = *reinterpret_cast<const f16x8*>(&lds[base + j * 1024 + c0]);
        b[j][1] = *reinterpret_cast<const f16x8*>(&lds[base + j * 1024 + c1]);
    }
}
template <int Q>
DEV void mfma16(const f16x8 (&a)[4][2], const f16x8 (&b)[2][2], f32x4 (&acc)[4][4][2]) {
    __builtin_amdgcn_s_setprio(1);
    #pragma unroll
    for (int i = 0; i < 4; i++)
        #pragma unroll
        for (int j = 0; j < 2; j++) {
            acc[Q][i][j] = __builtin_amdgcn_mfma_f32_16x16x32_f16(a[i][0], b[j][0], acc[Q][i][j], 0, 0, 0);
            acc[Q][i][j] = __builtin_amdgcn_mfma_f32_16x16x32_f16(a[i][1], b[j][1], acc[Q][i][j], 0, 0, 0);
        }
    __builtin_amdgcn_s_setprio(0);
}

template <int EPI>
__launch_bounds__(512)
__global__ void gemm256_k(const f16* __restrict__ A, const f16* __restrict__ B,
                          float* __restrict__ Cf, f16* __restrict__ Cs,
                          const float* __restrict__ bias,
                          int N, int K, long sA, long sB, long sC, int nbn) {
    extern __shared__ f16 lds[];   // 65536 f16 = 128 KiB: [buf][A|B][half][128*64]
    // --- XCD-aware bijective swizzle: grid is 1D, multiple of 8 ---
    const int nwg  = gridDim.x;
    const int cpx  = nwg >> 3;
    const int wgid = (blockIdx.x & 7) * cpx + (blockIdx.x >> 3);
    // decode: bz major, then bm, then bn (per_b tiles per batch)
    const int per_b = (EPI == 0) ? nwg : 16;
    const int bz  = wgid / per_b;
    const int rem = wgid % per_b;
    const int bm  = rem / nbn;
    const int bn  = rem % nbn;

    const int tid  = threadIdx.x;
    const int lane = tid & 63;
    const int w    = tid >> 6;          // 0..7
    const int wr   = w >> 2, wc = w & 3;
    const f16* Ab = A + (size_t)bz * sA + (size_t)(bm * 256) * K;
    const f16* Bb = B + (size_t)bz * sB + (size_t)(bn * 256) * K;
    // staging constants: lane -> (row-in-8, swizzled src slot)
    const int rloc = lane >> 3;                     // 0..7
    const int sl8  = ((lane & 7) ^ rloc) * 8;       // src k-offset (pre-swizzle)
    // frag-read constants: col = (kk*32 | 8*(lane>>4)) ^ (8*(lane&7))
    const int lrow = lane & 15;
    const int c0 = (8 * (lane >> 4)) ^ (8 * (lane & 7));
    const int c1 = c0 ^ 32;
    const int abase = (wr * 64 + lrow) * 64;
    const int bbase = (wc * 32 + lrow) * 64;

    auto stageA = [&](int sb, int half, int k0) {
        #pragma unroll
        for (int i = 0; i < 2; i++) {
            int rr = (w * 2 + i) * 8 + rloc;
            async_copy16(Ab + (size_t)(half * 128 + rr) * K + k0 + sl8,
                         &lds[sb + half * 8192 + (w * 2 + i) * 512 + lane * 8]);
        }
    };
    auto stageB = [&](int sb, int half, int k0) {
        #pragma unroll
        for (int i = 0; i < 2; i++) {
            int rr = (w * 2 + i) * 8 + rloc;
            async_copy16(Bb + (size_t)(half * 128 + rr) * K + k0 + sl8,
                         &lds[sb + 16384 + half * 8192 + (w * 2 + i) * 512 + lane * 8]);
        }
    };

    f32x4 acc[4][4][2] = {};
    const int nt = K >> 6;

    // prologue: stage tile 0 into buf 0 (order: A0,B0,B1,A1), wait A0,B0
    stageA(0, 0, 0); stageB(0, 0, 0);
    stageB(0, 1, 0); stageA(0, 1, 0);
    VMCNT(4);
    barfence();

    for (int t = 0; t < nt - 1; ++t) {
        const int cb = (t & 1) * 32768;
        const int sb = cb ^ 32768;
        const int kn = (t + 1) * 64;
        f16x8 af[4][2], bf0[2][2], bf1[2][2];
        // P0: A-half0 + B-half0 frags; stage A0',B0'
        load_af(lds, cb + abase, c0, c1, af);
        load_bf(lds, cb + 16384 + bbase, c0, c1, bf0);
        stageA(sb, 0, kn); stageB(sb, 0, kn);
        barfence();
        mfma16<0>(af, bf0, acc);      // (M0,N0)
        VMCNT(6);
        barfence();
        // P1: B-half1 frags; stage B1'
        load_bf(lds, cb + 16384 + 8192 + bbase, c0, c1, bf1);
        stageB(sb, 1, kn);
        barfence();
        mfma16<1>(af, bf1, acc);      // (M0,N1)
        VMCNT(6);
        barfence();
        // P2: A-half1 frags; stage A1'; two MFMA clusters
        load_af(lds, cb + 8192 + abase, c0, c1, af);
        stageA(sb, 1, kn);
        barfence();
        mfma16<2>(af, bf0, acc);      // (M1,N0)
        mfma16<3>(af, bf1, acc);      // (M1,N1)
        VMCNT(4);
        barfence();
    }
    // peeled last tile (no staging, strict waits)
    {
        const int cb = ((nt - 1) & 1) * 32768;
        f16x8 af[4][2], bf0[2][2], bf1[2][2];
        load_af(lds, cb + abase, c0, c1, af);
        load_bf(lds, cb + 16384 + bbase, c0, c1, bf0);
        barfence();
        mfma16<0>(af, bf0, acc);
        VMCNT(2);
        barfence();
        load_bf(lds, cb + 16384 + 8192 + bbase, c0, c1, bf1);
        barfence();
        mfma16<1>(af, bf1, acc);
        VMCNT(0);
        barfence();
        load_af(lds, cb + 8192 + abase, c0, c1, af);
        barfence();
        mfma16<2>(af, bf0, acc);
        mfma16<3>(af, bf1, acc);
    }

    // epilogue: q -> (mh=q>>1, nh=q&1)
    const int r4 = (lane >> 4) * 4, cl = lane & 15;
    #pragma unroll
    for (int q = 0; q < 4; q++)
        #pragma unroll
        for (int i = 0; i < 4; i++)
            #pragma unroll
            for (int j = 0; j < 2; j++) {
                const int row0 = bm * 256 + (q >> 1) * 128 + wr * 64 + i * 16 + r4;
                const int col  = bn * 256 + (q & 1) * 128 + wc * 32 + j * 16 + cl;
                if constexpr (EPI == 0) {
                    float bv = bias[col];
                    #pragma unroll
                    for (int r = 0; r < 4; r++) {
                        float v = acc[q][i][j][r] + bv;
                        f16 h = (f16)v;
                        size_t o = (size_t)(row0 + r) * (2 * N) + col;
                        Cs[o]     = h;
                        Cs[o + N] = (f16)(v - (float)h);
                    }
                } else {
                    #pragma unroll
                    for (int r = 0; r < 4; r++)
                        Cf[(size_t)bz * sC + (size_t)(row0 + r) * N + col] = acc[q][i][j][r];
                }
            }
}

// ---------------------------------------------------------------------------
// Row softmax: scores [rows][1024] fp32 -> attn [rows][1024] f16
__global__ void softmax_k(const float* __restrict__ S, f16* __restrict__ P) {
    __shared__ float red[8];
    const int row = blockIdx.x;
    const int t = threadIdx.x;
    const int wv = t >> 6, ln = t & 63;
    float4 v = reinterpret_cast<const float4*>(S + (size_t)row * 1024)[t];
    float m = fmaxf(fmaxf(v.x, v.y), fmaxf(v.z, v.w));
    #pragma unroll
    for (int off = 1; off < 64; off <<= 1) m = fmaxf(m, __shfl_xor(m, off));
    if (ln == 0) red[wv] = m;
    __syncthreads();
    m = fmaxf(fmaxf(red[0], red[1]), fmaxf(red[2], red[3]));
    float e0 = __expf(v.x - m), e1 = __expf(v.y - m), e2 = __expf(v.z - m), e3 = __expf(v.w - m);
    float s = e0 + e1 + e2 + e3;
    #pragma unroll
    for (int off = 1; off < 64; off <<= 1) s += __shfl_xor(s, off);
    if (ln == 0) red[4 + wv] = s;
    __syncthreads();
    s = red[4] + red[5] + red[6] + red[7];
    float inv = 1.0f / s;
    f16x4 o;
    o[0] = (f16)(e0 * inv); o[1] = (f16)(e1 * inv); o[2] = (f16)(e2 * inv); o[3] = (f16)(e3 * inv);
    *reinterpret_cast<f16x4*>(P + (size_t)row * 1024 + t * 4) = o;
}

// ---------------------------------------------------------------------------
extern "C" void kernel_launch(void* const* d_in, const int* in_sizes, int n_in,
                              void* d_out, int out_size, void* d_ws, size_t ws_size,
                              hipStream_t stream) {
    const float* text  = (const float*)d_in[0];  // [16,1024,1024]
    const float* local = (const float*)d_in[1];  // [16,1024,1024]
    const float* Ww    = (const float*)d_in[2];  // [1024,1024]
    const float* Wb    = (const float*)d_in[3];  // [1024]
    float* out = (float*)d_out;                  // [16,1024,1024] fp32

    char* ws = (char*)d_ws;
    const size_t MB = 1024 * 1024;
    f16*   textS  = (f16*)(ws);                 // 64MB (dead after proj)
    f16*   WS     = (f16*)(ws + 64 * MB);       //  4MB
    f16*   localS = (f16*)(ws + 68 * MB);       // 64MB
    f16*   localT = (f16*)(ws + 132 * MB);      // 32MB
    f16*   projS  = (f16*)(ws + 164 * MB);      // 64MB (dead after scores)
    float* scores = (float*)(ws);               // 64MB, reuses textS region
    f16*   attn   = (f16*)(ws + 164 * MB);      // 32MB, reuses projS region

    auto g0 = gemm256_k<0>;
    auto g1 = gemm256_k<1>;
    (void)hipFuncSetAttribute((const void*)g0, hipFuncAttributeMaxDynamicSharedMemorySize, 131072);
    (void)hipFuncSetAttribute((const void*)g1, hipFuncAttributeMaxDynamicSharedMemorySize, 131072);

    hipLaunchKernelGGL(split_rows_k, dim3(2048), dim3(256), 0, stream, text, textS, 16384 * 256);
    hipLaunchKernelGGL(split_rows_k, dim3(512), dim3(256), 0, stream, Ww, WS, 1024 * 256);
    hipLaunchKernelGGL(split_local_k, dim3(16, 16, 16), dim3(256), 0, stream,
                       local, localS, localT);
    // proj = text @ W^T + b  (M=16384, N=1024, K'=2048) -> split hi/lo
    // 1D grid 256, decode: bm = wgid/4, bn = wgid%4 (per_b = 256)
    hipLaunchKernelGGL(g0, dim3(256), dim3(512), 131072, stream,
                       textS, WS, (float*)nullptr, projS, Wb,
                       1024, 2048, 0L, 0L, 0L, 4);
    // scores[b] = proj[b] @ local[b]^T  (1024x1024, K'=2048)
    // 1D grid 256, decode: bz = wgid/16, bm = (wgid%16)/4, bn = wgid%4
    hipLaunchKernelGGL(g1, dim3(256), dim3(512), 131072, stream,
                       projS, localS, scores, (f16*)nullptr, (const float*)nullptr,
                       1024, 2048, (long)1024 * 2048, (long)1024 * 2048, (long)1024 * 1024, 4);
    hipLaunchKernelGGL(softmax_k, dim3(16384), dim3(256), 0, stream, scores, attn);
    // out[b] = attn[b] @ local[b]  (K=1024)
    hipLaunchKernelGGL(g1, dim3(256), dim3(512), 131072, stream,
                       attn, localT, out, (f16*)nullptr, (const float*)nullptr,
                       1024, 1024, (long)1024 * 1024, (long)1024 * 1024, (long)1024 * 1024, 4);
}

// Round 5
// 309.150 us; speedup vs baseline: 1.6132x; 1.2802x over previous
//
#include <hip/hip_runtime.h>
#include <hip/hip_fp16.h>

typedef _Float16 f16;
typedef _Float16 f16x8 __attribute__((ext_vector_type(8)));
typedef _Float16 f16x4 __attribute__((ext_vector_type(4)));
typedef float f32x4 __attribute__((ext_vector_type(4)));

#define DEV static __device__ __forceinline__
#define VMCNT(n) asm volatile("s_waitcnt vmcnt(" #n ")" ::: "memory")

DEV void barfence() {
    __builtin_amdgcn_s_barrier();
    asm volatile("" ::: "memory");
}

DEV void async_copy16(const f16* gsrc, f16* ldst) {
    __builtin_amdgcn_global_load_lds(
        (const __attribute__((address_space(1))) void*)gsrc,
        (__attribute__((address_space(3))) void*)ldst,
        16, 0, 0);
}

// ---------------------------------------------------------------------------
// fp32 -> f16 convert, grid-stride over float4s
__global__ void convert_f16_k(const float* __restrict__ src, f16* __restrict__ dst, int n4) {
    for (int idx = blockIdx.x * 256 + threadIdx.x; idx < n4; idx += gridDim.x * 256) {
        float4 v = reinterpret_cast<const float4*>(src)[idx];
        f16x4 o;
        o[0] = (f16)v.x; o[1] = (f16)v.y; o[2] = (f16)v.z; o[3] = (f16)v.w;
        *reinterpret_cast<f16x4*>(dst + (size_t)idx * 4) = o;
    }
}

// ---------------------------------------------------------------------------
// local [16][l][d] fp32 -> localF [16][l][1024] f16 and localT [16][d][1024 l] f16
__global__ void split_local_k(const float* __restrict__ local,
                              f16* __restrict__ localF, f16* __restrict__ localT) {
    __shared__ float tile[64][65];
    const int b  = blockIdx.z;
    const int l0 = blockIdx.y * 64;
    const int d0 = blockIdx.x * 64;
    const int r  = threadIdx.x >> 4;   // 0..15
    const int c4 = threadIdx.x & 15;   // 0..15
    const float* src = local + ((size_t)b * 1024 + l0) * 1024 + d0;
    #pragma unroll
    for (int rr = 0; rr < 4; rr++) {
        int row = rr * 16 + r;
        float4 v = *reinterpret_cast<const float4*>(src + (size_t)row * 1024 + c4 * 4);
        float vv[4] = {v.x, v.y, v.z, v.w};
        f16x4 hv;
        #pragma unroll
        for (int e = 0; e < 4; e++) {
            tile[row][c4 * 4 + e] = vv[e];
            hv[e] = (f16)vv[e];
        }
        *reinterpret_cast<f16x4*>(localF + ((size_t)b * 1024 + l0 + row) * 1024 + d0 + c4 * 4) = hv;
    }
    __syncthreads();
    #pragma unroll
    for (int rr = 0; rr < 4; rr++) {
        int d = rr * 16 + r;
        f16x4 o;
        #pragma unroll
        for (int e = 0; e < 4; e++) o[e] = (f16)tile[c4 * 4 + e][d];
        *reinterpret_cast<f16x4*>(localT + ((size_t)b * 1024 + d0 + d) * 1024 + l0 + c4 * 4) = o;
    }
}

// ---------------------------------------------------------------------------
// 256x256 tile, BK=64, 8 waves (2Mx4N), 3-phase pipelined K-loop, swizzled LDS,
// XCD-aware 1D block swizzle (contiguous wgid chunk per XCD).
// C[m,n] = sum_k A[m,k]*B[n,k].  EPI0: +bias -> f16 (ld N). EPI1: f32 (ld N).
DEV void load_af(const f16* lds, int base, int c0, int c1, f16x8 (&a)[4][2]) {
    #pragma unroll
    for (int i = 0; i < 4; i++) {
        a[i][0] = *reinterpret_cast<const f16x8*>(&lds[base + i * 1024 + c0]);
        a[i][1] = *reinterpret_cast<const f16x8*>(&lds[base + i * 1024 + c1]);
    }
}
DEV void load_bf(const f16* lds, int base, int c0, int c1, f16x8 (&b)[2][2]) {
    #pragma unroll
    for (int j = 0; j < 2; j++) {
        b[j][0] = *reinterpret_cast<const f16x8*>(&lds[base + j * 1024 + c0]);
        b[j][1] = *reinterpret_cast<const f16x8*>(&lds[base + j * 1024 + c1]);
    }
}
template <int Q>
DEV void mfma16(const f16x8 (&a)[4][2], const f16x8 (&b)[2][2], f32x4 (&acc)[4][4][2]) {
    __builtin_amdgcn_s_setprio(1);
    #pragma unroll
    for (int i = 0; i < 4; i++)
        #pragma unroll
        for (int j = 0; j < 2; j++) {
            acc[Q][i][j] = __builtin_amdgcn_mfma_f32_16x16x32_f16(a[i][0], b[j][0], acc[Q][i][j], 0, 0, 0);
            acc[Q][i][j] = __builtin_amdgcn_mfma_f32_16x16x32_f16(a[i][1], b[j][1], acc[Q][i][j], 0, 0, 0);
        }
    __builtin_amdgcn_s_setprio(0);
}

template <int EPI>
__launch_bounds__(512)
__global__ void gemm256_k(const f16* __restrict__ A, const f16* __restrict__ B,
                          float* __restrict__ Cf, f16* __restrict__ Cs,
                          const float* __restrict__ bias,
                          int N, int K, long sA, long sB, long sC, int nbn) {
    extern __shared__ f16 lds[];   // 65536 f16 = 128 KiB: [buf][A|B][half][128*64]
    // --- XCD-aware bijective swizzle: grid is 1D, multiple of 8 ---
    const int nwg  = gridDim.x;
    const int cpx  = nwg >> 3;
    const int wgid = (blockIdx.x & 7) * cpx + (blockIdx.x >> 3);
    // decode: bz major, then bm, then bn (per_b tiles per batch)
    const int per_b = (EPI == 0) ? nwg : 16;
    const int bz  = wgid / per_b;
    const int rem = wgid % per_b;
    const int bm  = rem / nbn;
    const int bn  = rem % nbn;

    const int tid  = threadIdx.x;
    const int lane = tid & 63;
    const int w    = tid >> 6;          // 0..7
    const int wr   = w >> 2, wc = w & 3;
    const f16* Ab = A + (size_t)bz * sA + (size_t)(bm * 256) * K;
    const f16* Bb = B + (size_t)bz * sB + (size_t)(bn * 256) * K;
    // staging constants: lane -> (row-in-8, swizzled src slot)
    const int rloc = lane >> 3;                     // 0..7
    const int sl8  = ((lane & 7) ^ rloc) * 8;       // src k-offset (pre-swizzle)
    // frag-read constants: col = (kk*32 | 8*(lane>>4)) ^ (8*(lane&7))
    const int lrow = lane & 15;
    const int c0 = (8 * (lane >> 4)) ^ (8 * (lane & 7));
    const int c1 = c0 ^ 32;
    const int abase = (wr * 64 + lrow) * 64;
    const int bbase = (wc * 32 + lrow) * 64;

    auto stageA = [&](int sb, int half, int k0) {
        #pragma unroll
        for (int i = 0; i < 2; i++) {
            int rr = (w * 2 + i) * 8 + rloc;
            async_copy16(Ab + (size_t)(half * 128 + rr) * K + k0 + sl8,
                         &lds[sb + half * 8192 + (w * 2 + i) * 512 + lane * 8]);
        }
    };
    auto stageB = [&](int sb, int half, int k0) {
        #pragma unroll
        for (int i = 0; i < 2; i++) {
            int rr = (w * 2 + i) * 8 + rloc;
            async_copy16(Bb + (size_t)(half * 128 + rr) * K + k0 + sl8,
                         &lds[sb + 16384 + half * 8192 + (w * 2 + i) * 512 + lane * 8]);
        }
    };

    f32x4 acc[4][4][2] = {};
    const int nt = K >> 6;

    // prologue: stage tile 0 into buf 0 (order: A0,B0,B1,A1), wait A0,B0
    stageA(0, 0, 0); stageB(0, 0, 0);
    stageB(0, 1, 0); stageA(0, 1, 0);
    VMCNT(4);
    barfence();

    for (int t = 0; t < nt - 1; ++t) {
        const int cb = (t & 1) * 32768;
        const int sb = cb ^ 32768;
        const int kn = (t + 1) * 64;
        f16x8 af[4][2], bf0[2][2], bf1[2][2];
        // P0: A-half0 + B-half0 frags; stage A0',B0'
        load_af(lds, cb + abase, c0, c1, af);
        load_bf(lds, cb + 16384 + bbase, c0, c1, bf0);
        stageA(sb, 0, kn); stageB(sb, 0, kn);
        barfence();
        mfma16<0>(af, bf0, acc);      // (M0,N0)
        VMCNT(6);
        barfence();
        // P1: B-half1 frags; stage B1'
        load_bf(lds, cb + 16384 + 8192 + bbase, c0, c1, bf1);
        stageB(sb, 1, kn);
        barfence();
        mfma16<1>(af, bf1, acc);      // (M0,N1)
        VMCNT(6);
        barfence();
        // P2: A-half1 frags; stage A1'; two MFMA clusters
        load_af(lds, cb + 8192 + abase, c0, c1, af);
        stageA(sb, 1, kn);
        barfence();
        mfma16<2>(af, bf0, acc);      // (M1,N0)
        mfma16<3>(af, bf1, acc);      // (M1,N1)
        VMCNT(4);
        barfence();
    }
    // peeled last tile (no staging, strict waits)
    {
        const int cb = ((nt - 1) & 1) * 32768;
        f16x8 af[4][2], bf0[2][2], bf1[2][2];
        load_af(lds, cb + abase, c0, c1, af);
        load_bf(lds, cb + 16384 + bbase, c0, c1, bf0);
        barfence();
        mfma16<0>(af, bf0, acc);
        VMCNT(2);
        barfence();
        load_bf(lds, cb + 16384 + 8192 + bbase, c0, c1, bf1);
        barfence();
        mfma16<1>(af, bf1, acc);
        VMCNT(0);
        barfence();
        load_af(lds, cb + 8192 + abase, c0, c1, af);
        barfence();
        mfma16<2>(af, bf0, acc);
        mfma16<3>(af, bf1, acc);
    }

    // epilogue: q -> (mh=q>>1, nh=q&1)
    const int r4 = (lane >> 4) * 4, cl = lane & 15;
    #pragma unroll
    for (int q = 0; q < 4; q++)
        #pragma unroll
        for (int i = 0; i < 4; i++)
            #pragma unroll
            for (int j = 0; j < 2; j++) {
                const int row0 = bm * 256 + (q >> 1) * 128 + wr * 64 + i * 16 + r4;
                const int col  = bn * 256 + (q & 1) * 128 + wc * 32 + j * 16 + cl;
                if constexpr (EPI == 0) {
                    float bv = bias[col];
                    #pragma unroll
                    for (int r = 0; r < 4; r++) {
                        float v = acc[q][i][j][r] + bv;
                        Cs[(size_t)(row0 + r) * N + col] = (f16)v;
                    }
                } else {
                    #pragma unroll
                    for (int r = 0; r < 4; r++)
                        Cf[(size_t)bz * sC + (size_t)(row0 + r) * N + col] = acc[q][i][j][r];
                }
            }
}

// ---------------------------------------------------------------------------
// Row softmax: scores [rows][1024] fp32 -> attn [rows][1024] f16
__global__ void softmax_k(const float* __restrict__ S, f16* __restrict__ P) {
    __shared__ float red[8];
    const int row = blockIdx.x;
    const int t = threadIdx.x;
    const int wv = t >> 6, ln = t & 63;
    float4 v = reinterpret_cast<const float4*>(S + (size_t)row * 1024)[t];
    float m = fmaxf(fmaxf(v.x, v.y), fmaxf(v.z, v.w));
    #pragma unroll
    for (int off = 1; off < 64; off <<= 1) m = fmaxf(m, __shfl_xor(m, off));
    if (ln == 0) red[wv] = m;
    __syncthreads();
    m = fmaxf(fmaxf(red[0], red[1]), fmaxf(red[2], red[3]));
    float e0 = __expf(v.x - m), e1 = __expf(v.y - m), e2 = __expf(v.z - m), e3 = __expf(v.w - m);
    float s = e0 + e1 + e2 + e3;
    #pragma unroll
    for (int off = 1; off < 64; off <<= 1) s += __shfl_xor(s, off);
    if (ln == 0) red[4 + wv] = s;
    __syncthreads();
    s = red[4] + red[5] + red[6] + red[7];
    float inv = 1.0f / s;
    f16x4 o;
    o[0] = (f16)(e0 * inv); o[1] = (f16)(e1 * inv); o[2] = (f16)(e2 * inv); o[3] = (f16)(e3 * inv);
    *reinterpret_cast<f16x4*>(P + (size_t)row * 1024 + t * 4) = o;
}

// ---------------------------------------------------------------------------
extern "C" void kernel_launch(void* const* d_in, const int* in_sizes, int n_in,
                              void* d_out, int out_size, void* d_ws, size_t ws_size,
                              hipStream_t stream) {
    const float* text  = (const float*)d_in[0];  // [16,1024,1024]
    const float* local = (const float*)d_in[1];  // [16,1024,1024]
    const float* Ww    = (const float*)d_in[2];  // [1024,1024]
    const float* Wb    = (const float*)d_in[3];  // [1024]
    float* out = (float*)d_out;                  // [16,1024,1024] fp32

    char* ws = (char*)d_ws;
    const size_t MB = 1024 * 1024;
    f16*   textF  = (f16*)(ws);                 // 32MB [16384][1024] (dead after proj)
    f16*   WF     = (f16*)(ws + 32 * MB);       //  2MB [1024][1024]
    f16*   localF = (f16*)(ws + 36 * MB);       // 32MB [16][l][1024]
    f16*   localT = (f16*)(ws + 68 * MB);       // 32MB [16][d][1024]
    f16*   projF  = (f16*)(ws + 100 * MB);      // 32MB [16384][1024]
    float* scores = (float*)(ws + 132 * MB);    // 64MB
    f16*   attn   = (f16*)(ws);                 // 32MB, reuses textF region

    auto g0 = gemm256_k<0>;
    auto g1 = gemm256_k<1>;
    (void)hipFuncSetAttribute((const void*)g0, hipFuncAttributeMaxDynamicSharedMemorySize, 131072);
    (void)hipFuncSetAttribute((const void*)g1, hipFuncAttributeMaxDynamicSharedMemorySize, 131072);

    hipLaunchKernelGGL(convert_f16_k, dim3(2048), dim3(256), 0, stream, text, textF, 16384 * 256);
    hipLaunchKernelGGL(convert_f16_k, dim3(512), dim3(256), 0, stream, Ww, WF, 1024 * 256);
    hipLaunchKernelGGL(split_local_k, dim3(16, 16, 16), dim3(256), 0, stream,
                       local, localF, localT);
    // proj = f16(text @ W^T + b)  (M=16384, N=1024, K=1024)
    // 1D grid 256, decode: bm = wgid/4, bn = wgid%4 (per_b = 256)
    hipLaunchKernelGGL(g0, dim3(256), dim3(512), 131072, stream,
                       textF, WF, (float*)nullptr, projF, Wb,
                       1024, 1024, 0L, 0L, 0L, 4);
    // scores[b] = proj[b] @ local[b]^T  (1024x1024, K=1024)
    // 1D grid 256, decode: bz = wgid/16, bm = (wgid%16)/4, bn = wgid%4
    hipLaunchKernelGGL(g1, dim3(256), dim3(512), 131072, stream,
                       projF, localF, scores, (f16*)nullptr, (const float*)nullptr,
                       1024, 1024, (long)1024 * 1024, (long)1024 * 1024, (long)1024 * 1024, 4);
    hipLaunchKernelGGL(softmax_k, dim3(16384), dim3(256), 0, stream, scores, attn);
    // out[b] = attn[b] @ local[b]  (K=1024)
    hipLaunchKernelGGL(g1, dim3(256), dim3(512), 131072, stream,
                       attn, localT, out, (f16*)nullptr, (const float*)nullptr,
                       1024, 1024, (long)1024 * 1024, (long)1024 * 1024, (long)1024 * 1024, 4);
}